// Round 12
// baseline (1715.344 us; speedup 1.0000x reference)
//
#include <hip/hip_runtime.h>

#define TT 2048
#define NB 512

__device__ __forceinline__ float rcpf(float x) { return __builtin_amdgcn_rcpf(x); }
__device__ __forceinline__ float fsig(float x) { return rcpf(1.0f + __expf(-x)); }
__device__ __forceinline__ float ftanh(float x) {
    return fmaf(2.0f, rcpf(1.0f + __expf(-2.0f * x)), -1.0f);
}

template<int C>
__device__ __forceinline__ float dppmov(float s) {
    return __int_as_float(__builtin_amdgcn_update_dpp(
        __float_as_int(s), __float_as_int(s), C, 0xF, 0xF, false));
}
// Full wave64 sum, result in lane 63 (verified R6-R11).
__device__ __forceinline__ float wave_sum63(float s) {
    s += dppmov<0x111>(s); s += dppmov<0x112>(s); s += dppmov<0x114>(s);
    s += dppmov<0x118>(s); s += dppmov<0x142>(s); s += dppmov<0x143>(s);
    return s;
}
template<int Q>
__device__ __forceinline__ float qbcast(float x) {
    return __int_as_float(__builtin_amdgcn_update_dpp(
        __float_as_int(x), __float_as_int(x), Q * 0x55, 0xF, 0xF, false));
}
// Wave-uniform broadcast of lane k's value: VALU pipe, no LDS.
#define RL(k) __int_as_float(__builtin_amdgcn_readlane(__float_as_int(hl), (k)))

// 512 blocks x 4 waves, 1 elem/block, 2 blocks/CU (8 waves = 2/SIMD).
// THE FIX vs R6-R11: h1 broadcast moves off the LDS pipe. Model (fits R2/R6/
// R8/R11 within ~10%): LDS costs ~12 cyc PER OP on the single per-CU LDS
// unit; the uniform-b128 h-broadcast is layout-invariant at 128 ops/CU/step
// -> ~1800 cyc/step floor, which matched every measured round. Here each
// wave does ONE strided ds_read_b32 (lane l -> h[l]) and 64 v_readlane
// (VALU, 4 pipes/CU) to broadcast -> ~22 LDS ops/CU/step total.
// Layout: R6-proven quad-gate (lane=4u'+g, unit=wave*16+u', full-K column
// per lane, 64 named-scalar register weights per R4's residency recipe),
// qbcast gate exchange (VALU), ONE barrier/step, parity-dbuf h1row.
// Layer-2: DPP wave_sum reusing the SAME strided read value (gate=wave);
// scalar chain wave2/lane0 (2-lag, zp ring); h2 staged in LDS, flushed as
// one coalesced 64-float store per 64 steps by wave0 after the barrier.
__global__ __launch_bounds__(256)
__attribute__((amdgpu_waves_per_eu(2, 2)))
void lstm2_kernel(const float* __restrict__ x,
                  const float* __restrict__ W1,
                  const float* __restrict__ b1,
                  const float* __restrict__ W2,
                  const float* __restrict__ b2,
                  float* __restrict__ out)
{
    __shared__ __align__(16) float xall[TT + 4];
    __shared__ __align__(16) float h1row[2][64];   // parity-dbuf h1
    __shared__ __align__(16) float zp[4][4];       // layer-2 partial ring
    __shared__ __align__(16) float h2buf[2][64];   // h2 staging ring

    const int tid  = threadIdx.x;
    const int wave = tid >> 6;
    const int lane = tid & 63;
    const int b    = blockIdx.x;

    for (int i = tid; i < TT; i += 256) xall[i] = x[b * TT + i];
    if (tid < 4) xall[TT + tid] = 0.0f;

    const int g    = lane & 3;          // gate i,j,f,o
    const int u    = lane >> 2;         // local unit 0..15
    const int unit = (wave << 4) + u;   // global unit 0..63
    const int col  = (g << 6) + unit;   // W1 (65,256) column

    // 64 named scalar weights (rows 1..64 = h-part), R4-verified residency.
#define DECLW(q) \
    const float wx##q = W1[(4*(q)+1)*256 + col]; \
    const float wy##q = W1[(4*(q)+2)*256 + col]; \
    const float wz##q = W1[(4*(q)+3)*256 + col]; \
    const float ww##q = W1[(4*(q)+4)*256 + col];
    DECLW(0)  DECLW(1)  DECLW(2)  DECLW(3)
    DECLW(4)  DECLW(5)  DECLW(6)  DECLW(7)
    DECLW(8)  DECLW(9)  DECLW(10) DECLW(11)
    DECLW(12) DECLW(13) DECLW(14) DECLW(15)
#undef DECLW

    const float w0x   = W1[col];                       // x-part row 0
    const float biasF = b1[col] + ((g == 2) ? 1.0f : 0.0f);  // fold forget bias
    const float nlm   = (g == 1) ? -2.0f : -1.0f;
    const bool  isj   = (g == 1);

    const float w2g  = W2[lane * 4 + wave];            // layer-2, gate = wave
    const float w2h0 = W2[256], w2h1 = W2[257], w2h2 = W2[258], w2h3 = W2[259];
    const float b20 = b2[0], b21 = b2[1], b22 = b2[2], b23 = b2[3];

    float c1 = 0.0f;                 // redundant per quad
    float c2 = 0.0f, h2v = 0.0f;     // layer-2 state (wave2/lane0)

    if (tid < 64) h1row[0][tid] = 0.0f;
    __syncthreads();

    float* __restrict__ outb = out + b * TT;

#define STEP(P, t, xv)                                                        \
    {                                                                         \
        if ((t) < TT) {                                                       \
            const float hl = h1row[P][lane];   /* strided b32: 1 LDS op */    \
            float a0 = fmaf((xv), w0x, biasF);                                \
            float a1 = 0.f, a2 = 0.f, a3 = 0.f;                               \
            FMA4(0)  FMA4(1)  FMA4(2)  FMA4(3)                                \
            FMA4(4)  FMA4(5)  FMA4(6)  FMA4(7)                                \
            FMA4(8)  FMA4(9)  FMA4(10) FMA4(11)                               \
            FMA4(12) FMA4(13) FMA4(14) FMA4(15)                               \
            const float acc = (a0 + a1) + (a2 + a3);                          \
            const float e = __expf(acc * nlm);                                \
            const float r = rcpf(1.0f + e);                                   \
            const float v = isj ? fmaf(2.0f, r, -1.0f) : r;                   \
            const float gi = qbcast<0>(v), gj = qbcast<1>(v);                 \
            const float gf = qbcast<2>(v), go = qbcast<3>(v);                 \
            c1 = fmaf(c1, gf, gi * gj);                                       \
            const float h1v = ftanh(c1) * go;                                 \
            if (g == 0) h1row[(P) ^ 1][unit] = h1v;                           \
        }                                                                     \
        if ((t) >= 1 && (t) <= TT) {   /* layer-2 partial for step t-1 */     \
            const float hs = h1row[P][lane];   /* CSEs with phase-A read */   \
            const float s  = wave_sum63(hs * w2g);                            \
            if (lane == 63) zp[((t) - 1) & 3][wave] = s;                      \
        }                                                                     \
        if (wave == 2 && lane == 0 && (t) >= 2 && (t) <= TT + 1) {            \
            const int st = (t) - 2;                                           \
            const float4 z4 = *(const float4*)zp[st & 3];                     \
            const float zi = z4.x + fmaf(h2v, w2h0, b20);                     \
            const float zj = z4.y + fmaf(h2v, w2h1, b21);                     \
            const float zf = z4.z + fmaf(h2v, w2h2, b22);                     \
            const float zo = z4.w + fmaf(h2v, w2h3, b23);                     \
            c2 = c2 * fsig(zf + 1.0f) + fsig(zi) * ftanh(zj);                 \
            h2v = ftanh(c2) * fsig(zo);                                       \
            h2buf[(st >> 6) & 1][st & 63] = h2v;                              \
        }                                                                     \
        __syncthreads();               /* the ONLY barrier per step */        \
        if (wave == 0 && (t) >= 66 && ((t) & 63) == 2) {                      \
            const int blk = ((t) - 66) >> 6;                                  \
            outb[(blk << 6) + lane] = h2buf[blk & 1][lane];                   \
        }                                                                     \
    }

#define FMA4(q)                                                               \
    a0 = fmaf(RL(4*(q)+0), wx##q, a0);                                        \
    a1 = fmaf(RL(4*(q)+1), wy##q, a1);                                        \
    a2 = fmaf(RL(4*(q)+2), wz##q, a2);                                        \
    a3 = fmaf(RL(4*(q)+3), ww##q, a3);

    for (int it = 0; it <= TT + 2; it += 2) {
        const float2 x2 = *(const float2*)&xall[it];
        STEP(0, it,     x2.x)
        STEP(1, it + 1, x2.y)
    }
#undef FMA4
#undef STEP
}

extern "C" void kernel_launch(void* const* d_in, const int* in_sizes, int n_in,
                              void* d_out, int out_size, void* d_ws, size_t ws_size,
                              hipStream_t stream)
{
    const float* x  = (const float*)d_in[0];
    const float* W1 = (const float*)d_in[1];
    const float* b1 = (const float*)d_in[2];
    const float* W2 = (const float*)d_in[3];
    const float* b2 = (const float*)d_in[4];
    float* out = (float*)d_out;
    lstm2_kernel<<<NB, 256, 0, stream>>>(x, W1, b1, W2, b2, out);
}

// Round 13
// 1408.097 us; speedup vs baseline: 1.2182x; 1.2182x over previous
//
#include <hip/hip_runtime.h>

#define TT 2048
#define NB 512

typedef float v2f __attribute__((ext_vector_type(2)));

__device__ __forceinline__ v2f mk2(float a, float b) { v2f r; r.x = a; r.y = b; return r; }
__device__ __forceinline__ float rcpf(float x) { return __builtin_amdgcn_rcpf(x); }
__device__ __forceinline__ float fsig(float x) { return rcpf(1.0f + __expf(-x)); }
__device__ __forceinline__ float ftanh(float x) {
    return fmaf(2.0f, rcpf(1.0f + __expf(-2.0f * x)), -1.0f);
}

template<int C>
__device__ __forceinline__ float dppmov(float s) {
    return __int_as_float(__builtin_amdgcn_update_dpp(
        __float_as_int(s), __float_as_int(s), C, 0xF, 0xF, false));
}
// Full wave64 sum, result in lane 63 (verified R6-R12).
__device__ __forceinline__ float wave_sum63(float s) {
    s += dppmov<0x111>(s); s += dppmov<0x112>(s); s += dppmov<0x114>(s);
    s += dppmov<0x118>(s); s += dppmov<0x142>(s); s += dppmov<0x143>(s);
    return s;
}
template<int Q>
__device__ __forceinline__ float qbcast(float x) {
    return __int_as_float(__builtin_amdgcn_update_dpp(
        __float_as_int(x), __float_as_int(x), Q * 0x55, 0xF, 0xF, false));
}

// ===================== Kernel 1: layer 1 + zp partials =====================
// R11's proven split-K core (lane = 8u'+4h+g, bank-disjoint halves, pk-FMA,
// DPP half-combine, qbcast gate exchange, ONE barrier/step) with the layer-2
// scalar chain REMOVED (it was the per-step barrier straggler: phase A plus
// ~10 quarter-rate trans ops on wave7 delayed every barrier by ~200 cyc).
// zp partials go to a 32-deep LDS ring, flushed to global (d_ws) every 16
// steps by a rotating wave. Kernel 2 consumes them.
__global__ __launch_bounds__(512)
__attribute__((amdgpu_waves_per_eu(4, 4)))
void lstm1_kernel(const float* __restrict__ x,
                  const float* __restrict__ W1,
                  const float* __restrict__ b1,
                  const float* __restrict__ W2,
                  float* __restrict__ zout)
{
    __shared__ __align__(16) float xall[TT + 4];
    __shared__ __align__(16) float h1x[2][80];   // halves at [0..31],[48..79]
    __shared__ __align__(16) float zpr[32][4];   // layer-2 partial ring

    const int tid  = threadIdx.x;
    const int wave = tid >> 6;
    const int lane = tid & 63;
    const int b    = blockIdx.x;

    for (int i = tid; i < TT; i += 512) xall[i] = x[b * TT + i];
    if (tid < 4) xall[TT + tid] = 0.0f;

    const int u    = lane >> 3;          // unit-in-wave 0..7
    const int h    = (lane >> 2) & 1;    // K-half
    const int g    = lane & 3;           // gate i,j,f,o
    const int unit = (wave << 3) + u;    // global unit 0..63
    const int col  = (g << 6) + unit;    // W1 (65,256) column

#define DECLW(k) const v2f wp##k = mk2(W1[(1 + 32*h + 2*(k)) * 256 + col], \
                                       W1[(2 + 32*h + 2*(k)) * 256 + col]);
    DECLW(0)  DECLW(1)  DECLW(2)  DECLW(3)
    DECLW(4)  DECLW(5)  DECLW(6)  DECLW(7)
    DECLW(8)  DECLW(9)  DECLW(10) DECLW(11)
    DECLW(12) DECLW(13) DECLW(14) DECLW(15)
#undef DECLW

    const float w0x   = (h == 0) ? W1[col] : 0.0f;   // x-part (half 0 only)
    const float biasF = (h == 0) ? (b1[col] + ((g == 2) ? 1.0f : 0.0f)) : 0.0f;
    const float nlm   = (g == 1) ? -2.0f : -1.0f;
    const bool  isj   = (g == 1);

    const float w2g = W2[lane * 4 + (wave & 3)];     // waves 0-3: gate = wave

    float c1 = 0.0f;                                 // redundant per octet

    const int hbase = h * 48;
    const int ridx  = lane + ((lane >> 5) << 4);
    const int widx  = (unit < 32) ? unit : unit + 16;

    if (tid < 160) ((float*)h1x)[tid] = 0.0f;
    __syncthreads();

    float* __restrict__ zb = zout + (size_t)b * TT * 4;

#define STEP(P, t, xv)                                                        \
    {                                                                         \
        if ((t) < TT) {                                                       \
            const float4* hp = (const float4*)&h1x[P][hbase];                 \
            const float4 q0 = hp[0], q1 = hp[1], q2 = hp[2], q3 = hp[3];      \
            const float4 q4 = hp[4], q5 = hp[5], q6 = hp[6], q7 = hp[7];      \
            v2f a0 = mk2(fmaf((xv), w0x, biasF), 0.0f);                       \
            v2f a1 = mk2(0.f, 0.f), a2 = mk2(0.f, 0.f), a3 = mk2(0.f, 0.f);  \
            a0 = __builtin_elementwise_fma(mk2(q0.x, q0.y), wp0,  a0);        \
            a1 = __builtin_elementwise_fma(mk2(q0.z, q0.w), wp1,  a1);        \
            a2 = __builtin_elementwise_fma(mk2(q1.x, q1.y), wp2,  a2);        \
            a3 = __builtin_elementwise_fma(mk2(q1.z, q1.w), wp3,  a3);        \
            a0 = __builtin_elementwise_fma(mk2(q2.x, q2.y), wp4,  a0);        \
            a1 = __builtin_elementwise_fma(mk2(q2.z, q2.w), wp5,  a1);        \
            a2 = __builtin_elementwise_fma(mk2(q3.x, q3.y), wp6,  a2);        \
            a3 = __builtin_elementwise_fma(mk2(q3.z, q3.w), wp7,  a3);        \
            a0 = __builtin_elementwise_fma(mk2(q4.x, q4.y), wp8,  a0);        \
            a1 = __builtin_elementwise_fma(mk2(q4.z, q4.w), wp9,  a1);        \
            a2 = __builtin_elementwise_fma(mk2(q5.x, q5.y), wp10, a2);        \
            a3 = __builtin_elementwise_fma(mk2(q5.z, q5.w), wp11, a3);        \
            a0 = __builtin_elementwise_fma(mk2(q6.x, q6.y), wp12, a0);        \
            a1 = __builtin_elementwise_fma(mk2(q6.z, q6.w), wp13, a1);        \
            a2 = __builtin_elementwise_fma(mk2(q7.x, q7.y), wp14, a2);        \
            a3 = __builtin_elementwise_fma(mk2(q7.z, q7.w), wp15, a3);        \
            const v2f sv = (a0 + a1) + (a2 + a3);                             \
            const float zh = sv.x + sv.y;                                     \
            const float tshr = dppmov<0x114>(zh);   /* from lane i-4 */       \
            const float tshl = dppmov<0x104>(zh);   /* from lane i+4 */       \
            const float zfull = zh + (h ? tshr : tshl);                       \
            const float e = __expf(zfull * nlm);                              \
            const float r = rcpf(1.0f + e);                                   \
            const float v = isj ? fmaf(2.0f, r, -1.0f) : r;                   \
            const float gi = qbcast<0>(v), gj = qbcast<1>(v);                 \
            const float gf = qbcast<2>(v), go = qbcast<3>(v);                 \
            c1 = fmaf(c1, gf, gi * gj);                                       \
            const float h1v = ftanh(c1) * go;                                 \
            if ((lane & 7) == 0) h1x[(P) ^ 1][widx] = h1v;                    \
        }                                                                     \
        if (wave < 4 && (t) >= 1 && (t) <= TT) {                              \
            const float s = wave_sum63(h1x[P][ridx] * w2g);                   \
            if (lane == 63) zpr[((t) - 1) & 31][wave] = s;                    \
        }                                                                     \
        __syncthreads();                                                      \
        if ((t) >= 16 && (t) <= TT && ((t) & 15) == 0 &&                      \
            wave == (((t) >> 4) & 7)) {                                       \
            const int base = (t) - 16;                                        \
            const float zv = ((const float*)zpr)[((base & 31) << 2) + lane];  \
            zb[(size_t)(base << 2) + lane] = zv;                              \
        }                                                                     \
    }

    for (int it = 0; it <= TT + 2; it += 2) {
        const float2 x2 = *(const float2*)&xall[it];
        STEP(0, it,     x2.x)
        STEP(1, it + 1, x2.y)
    }
#undef STEP
}

// ===================== Kernel 2: layer-2 recurrence =====================
// 32 blocks x 1 wave; 16 elements per wave, 4 lanes (= 4 gates) per element.
// The 4 gate nonlins vectorize into ONE exp + ONE rcp per step; gate values
// exchanged via qbcast; 16 independent chains run SIMD-parallel. No barriers.
__global__ __launch_bounds__(64)
void lstm2_chain(const float* __restrict__ zp,
                 const float* __restrict__ W2,
                 const float* __restrict__ b2,
                 float* __restrict__ out)
{
    const int lane = threadIdx.x & 63;
    const int e    = lane >> 2;                 // element-in-wave 0..15
    const int g    = lane & 3;                  // gate i,j,f,o
    const int elem = (blockIdx.x << 4) + e;

    const float w2h = W2[256 + g];              // h2 recurrent weight, row 64
    const float bb  = b2[g] + ((g == 2) ? 1.0f : 0.0f);   // fold forget bias
    const float nlm = (g == 1) ? -2.0f : -1.0f;
    const float k2  = (g == 1) ?  2.0f :  1.0f;
    const float k3  = (g == 1) ? -1.0f :  0.0f;

    const float* __restrict__ zrow = zp + (size_t)elem * TT * 4 + g;
    float* __restrict__ orow = out + (size_t)elem * TT;

    float c2 = 0.0f, h2 = 0.0f;                 // quad-uniform chain state

    float zc[16];
#pragma unroll
    for (int k = 0; k < 16; ++k) zc[k] = zrow[k << 2];

    for (int t0 = 0; t0 < TT; t0 += 16) {
        float zn[16];
        if (t0 + 16 < TT) {
#pragma unroll
            for (int k = 0; k < 16; ++k) zn[k] = zrow[((t0 + 16 + k) << 2)];
        }
        float st0 = 0.f, st1 = 0.f, st2 = 0.f, st3 = 0.f;
#pragma unroll
        for (int k = 0; k < 16; ++k) {
            const float arg = fmaf(w2h, h2, zc[k] + bb);
            const float ev  = __expf(arg * nlm);
            const float rv  = rcpf(1.0f + ev);
            const float v   = fmaf(k2, rv, k3);   // sig / tanh per gate lane
            const float vi = qbcast<0>(v), vj = qbcast<1>(v);
            const float vf = qbcast<2>(v), vo = qbcast<3>(v);
            c2 = fmaf(c2, vf, vi * vj);
            h2 = ftanh(c2) * vo;
            const bool mine = (g == (k & 3));
            if ((k >> 2) == 0) st0 = mine ? h2 : st0;
            else if ((k >> 2) == 1) st1 = mine ? h2 : st1;
            else if ((k >> 2) == 2) st2 = mine ? h2 : st2;
            else st3 = mine ? h2 : st3;
        }
        orow[t0 + g]      = st0;   // lane g holds steps t0 + 4a + g
        orow[t0 + 4 + g]  = st1;
        orow[t0 + 8 + g]  = st2;
        orow[t0 + 12 + g] = st3;
#pragma unroll
        for (int k = 0; k < 16; ++k) zc[k] = zn[k];
    }
}

// ===================== Fallback: R11 monolithic (proven 1532 us) ==========
__global__ __launch_bounds__(512)
__attribute__((amdgpu_waves_per_eu(4, 4)))
void lstm2_mono(const float* __restrict__ x,
                const float* __restrict__ W1,
                const float* __restrict__ b1,
                const float* __restrict__ W2,
                const float* __restrict__ b2,
                float* __restrict__ out)
{
    __shared__ __align__(16) float xall[TT + 4];
    __shared__ __align__(16) float h1x[2][80];
    __shared__ __align__(16) float zpq[4][4];
    __shared__ __align__(16) float h2buf[2][64];

    const int tid  = threadIdx.x;
    const int wave = tid >> 6;
    const int lane = tid & 63;
    const int b    = blockIdx.x;

    for (int i = tid; i < TT; i += 512) xall[i] = x[b * TT + i];
    if (tid < 4) xall[TT + tid] = 0.0f;

    const int u    = lane >> 3;
    const int h    = (lane >> 2) & 1;
    const int g    = lane & 3;
    const int unit = (wave << 3) + u;
    const int col  = (g << 6) + unit;

#define DECLW(k) const v2f wp##k = mk2(W1[(1 + 32*h + 2*(k)) * 256 + col], \
                                       W1[(2 + 32*h + 2*(k)) * 256 + col]);
    DECLW(0)  DECLW(1)  DECLW(2)  DECLW(3)
    DECLW(4)  DECLW(5)  DECLW(6)  DECLW(7)
    DECLW(8)  DECLW(9)  DECLW(10) DECLW(11)
    DECLW(12) DECLW(13) DECLW(14) DECLW(15)
#undef DECLW

    const float w0x   = (h == 0) ? W1[col] : 0.0f;
    const float biasF = (h == 0) ? (b1[col] + ((g == 2) ? 1.0f : 0.0f)) : 0.0f;
    const float nlm   = (g == 1) ? -2.0f : -1.0f;
    const bool  isj   = (g == 1);

    const float w2g  = W2[lane * 4 + (wave & 3)];
    const float w2h0 = W2[256], w2h1 = W2[257], w2h2 = W2[258], w2h3 = W2[259];
    const float b20 = b2[0], b21 = b2[1], b22 = b2[2], b23 = b2[3];

    float c1 = 0.0f;
    float c2 = 0.0f, h2v = 0.0f;

    const int hbase = h * 48;
    const int ridx  = lane + ((lane >> 5) << 4);
    const int widx  = (unit < 32) ? unit : unit + 16;

    if (tid < 160) ((float*)h1x)[tid] = 0.0f;
    __syncthreads();

    float* __restrict__ outb = out + b * TT;

#define STEP(P, t, xv)                                                        \
    {                                                                         \
        if ((t) < TT) {                                                       \
            const float4* hp = (const float4*)&h1x[P][hbase];                 \
            const float4 q0 = hp[0], q1 = hp[1], q2 = hp[2], q3 = hp[3];      \
            const float4 q4 = hp[4], q5 = hp[5], q6 = hp[6], q7 = hp[7];      \
            v2f a0 = mk2(fmaf((xv), w0x, biasF), 0.0f);                       \
            v2f a1 = mk2(0.f, 0.f), a2 = mk2(0.f, 0.f), a3 = mk2(0.f, 0.f);  \
            a0 = __builtin_elementwise_fma(mk2(q0.x, q0.y), wp0,  a0);        \
            a1 = __builtin_elementwise_fma(mk2(q0.z, q0.w), wp1,  a1);        \
            a2 = __builtin_elementwise_fma(mk2(q1.x, q1.y), wp2,  a2);        \
            a3 = __builtin_elementwise_fma(mk2(q1.z, q1.w), wp3,  a3);        \
            a0 = __builtin_elementwise_fma(mk2(q2.x, q2.y), wp4,  a0);        \
            a1 = __builtin_elementwise_fma(mk2(q2.z, q2.w), wp5,  a1);        \
            a2 = __builtin_elementwise_fma(mk2(q3.x, q3.y), wp6,  a2);        \
            a3 = __builtin_elementwise_fma(mk2(q3.z, q3.w), wp7,  a3);        \
            a0 = __builtin_elementwise_fma(mk2(q4.x, q4.y), wp8,  a0);        \
            a1 = __builtin_elementwise_fma(mk2(q4.z, q4.w), wp9,  a1);        \
            a2 = __builtin_elementwise_fma(mk2(q5.x, q5.y), wp10, a2);        \
            a3 = __builtin_elementwise_fma(mk2(q5.z, q5.w), wp11, a3);        \
            a0 = __builtin_elementwise_fma(mk2(q6.x, q6.y), wp12, a0);        \
            a1 = __builtin_elementwise_fma(mk2(q6.z, q6.w), wp13, a1);        \
            a2 = __builtin_elementwise_fma(mk2(q7.x, q7.y), wp14, a2);        \
            a3 = __builtin_elementwise_fma(mk2(q7.z, q7.w), wp15, a3);        \
            const v2f sv = (a0 + a1) + (a2 + a3);                             \
            const float zh = sv.x + sv.y;                                     \
            const float tshr = dppmov<0x114>(zh);                             \
            const float tshl = dppmov<0x104>(zh);                             \
            const float zfull = zh + (h ? tshr : tshl);                       \
            const float e = __expf(zfull * nlm);                              \
            const float r = rcpf(1.0f + e);                                   \
            const float v = isj ? fmaf(2.0f, r, -1.0f) : r;                   \
            const float gi = qbcast<0>(v), gj = qbcast<1>(v);                 \
            const float gf = qbcast<2>(v), go = qbcast<3>(v);                 \
            c1 = fmaf(c1, gf, gi * gj);                                       \
            const float h1v = ftanh(c1) * go;                                 \
            if ((lane & 7) == 0) h1x[(P) ^ 1][widx] = h1v;                    \
        }                                                                     \
        if (wave < 4 && (t) >= 1 && (t) <= TT) {                              \
            const float s = wave_sum63(h1x[P][ridx] * w2g);                   \
            if (lane == 63) zpq[((t) - 1) & 3][wave] = s;                     \
        }                                                                     \
        if (wave == 7 && lane == 0 && (t) >= 2 && (t) <= TT + 1) {            \
            const int st = (t) - 2;                                           \
            const float4 z4 = *(const float4*)zpq[st & 3];                    \
            const float zi = z4.x + fmaf(h2v, w2h0, b20);                     \
            const float zj = z4.y + fmaf(h2v, w2h1, b21);                     \
            const float zf = z4.z + fmaf(h2v, w2h2, b22);                     \
            const float zo = z4.w + fmaf(h2v, w2h3, b23);                     \
            c2 = c2 * fsig(zf + 1.0f) + fsig(zi) * ftanh(zj);                 \
            h2v = ftanh(c2) * fsig(zo);                                       \
            h2buf[(st >> 6) & 1][st & 63] = h2v;                              \
        }                                                                     \
        __syncthreads();                                                      \
        if (wave == 4 && (t) >= 66 && ((t) & 63) == 2) {                      \
            const int blk = ((t) - 66) >> 6;                                  \
            outb[(blk << 6) + lane] = h2buf[blk & 1][lane];                   \
        }                                                                     \
    }

    for (int it = 0; it <= TT + 2; it += 2) {
        const float2 x2 = *(const float2*)&xall[it];
        STEP(0, it,     x2.x)
        STEP(1, it + 1, x2.y)
    }
#undef STEP
}

extern "C" void kernel_launch(void* const* d_in, const int* in_sizes, int n_in,
                              void* d_out, int out_size, void* d_ws, size_t ws_size,
                              hipStream_t stream)
{
    const float* x  = (const float*)d_in[0];
    const float* W1 = (const float*)d_in[1];
    const float* b1 = (const float*)d_in[2];
    const float* W2 = (const float*)d_in[3];
    const float* b2 = (const float*)d_in[4];
    float* out = (float*)d_out;

    const size_t need = (size_t)NB * TT * 4 * sizeof(float);   // 16.8 MB
    if (ws_size >= need) {
        float* zp = (float*)d_ws;
        lstm1_kernel<<<NB, 512, 0, stream>>>(x, W1, b1, W2, zp);
        lstm2_chain<<<NB / 16, 64, 0, stream>>>(zp, W2, b2, out);
    } else {
        lstm2_mono<<<NB, 512, 0, stream>>>(x, W1, b1, W2, b2, out);
    }
}